// Round 3
// baseline (181.396 us; speedup 1.0000x reference)
//
#include <hip/hip_runtime.h>
#include <hip/hip_bf16.h>
#include <cstdint>
#include <cstddef>

typedef short short8 __attribute__((ext_vector_type(8)));
typedef float f32x4 __attribute__((ext_vector_type(4)));

#define NS    2048
#define KPAD  288     // 285 sig channels padded to 288
#define H2    512
#define HID   256
#define WPB   14      // windows per sig workgroup (2 waves x 7)
#define SBLK  147     // ceil(2048/14)

// async global->LDS 16B: dst must be the WAVE-UNIFORM base; lane i lands at dst + i*16
__device__ __forceinline__ void gl2lds16(const void* g, void* l) {
    __builtin_amdgcn_global_load_lds(
        (const __attribute__((address_space(1))) void*)g,
        (__attribute__((address_space(3))) void*)l, 16, 0, 0);
}

// ---- compile-time necklace-representative table: (i,j,k) -> feat col (45+rank) or -1
struct Tbl3 { short col[729]; };
static constexpr Tbl3 make_tbl3() {
    Tbl3 t{};
    for (int x = 0; x < 729; ++x) t.col[x] = -1;
    int r = 0;
    for (int i = 0; i < 9; ++i)
        for (int j = 0; j < 9; ++j)
            for (int k = 0; k < 9; ++k) {
                bool lt1 = (i < j) || (i == j && (j < k || (j == k && k < i)));
                bool lt2 = (i < k) || (i == k && (j < i || (j == i && k < j)));
                if (lt1 && lt2) { t.col[(i*9+j)*9+k] = (short)(45 + r); ++r; }
            }
    return t;
}
static constexpr Tbl3 TBL3 = make_tbl3();

// ============================================================================
// Signature kernel: one lane per (window, slab i).  Lane keeps S3[i][.][.]
// (81 regs), S2 row i (9), S1_i.  128 threads = 2 waves = 14 windows/block.
// amdgpu_waves_per_eu(1,3): MAX=3 waves/EU is what raises the VGPR budget to
// ~170 (r1/r2 lesson: min-only forms leave the default 6-7 wave target ->
// 72-84 VGPR -> S3 pressure-spilled -> 9.2 GB scratch writes, 61-92 us).
// ============================================================================
__global__ __launch_bounds__(128) __attribute__((amdgpu_waves_per_eu(1, 3)))
void sig_kernel(const float* __restrict__ x, __hip_bfloat16* __restrict__ feats) {
    __shared__ __align__(16) float X[73 * 8];
    __shared__ float S2buf[WPB * 81];
    __shared__ float S1buf[WPB * 9];

    const int blk = blockIdx.x;
    const int b   = blk / SBLK;
    const int s0  = (blk % SBLK) * WPB;
    const int lo  = (s0 - 59 > 0) ? (s0 - 59) : 0;
    const int hi  = (s0 + WPB - 1 < NS - 1) ? (s0 + WPB - 1) : (NS - 1);
    const int nrow = hi - lo + 1;     // <= 73
    const int tid = threadIdx.x;

    {   // stage x[b, lo..hi, 0..7] -> LDS (row-major [pos][ch])
        const float4* src = (const float4*)(x + ((size_t)b * NS + lo) * 8);
        float4* dst = (float4*)X;
        const int n4 = nrow * 2;
        for (int t = tid; t < n4; t += 128) dst[t] = src[t];
    }
    __syncthreads();

    const int lane = tid & 63;
    const int wave = tid >> 6;
    const int wl   = lane / 9;            // 0..7 (7 == idle duplicate lane)
    const int ci   = lane - wl * 9;       // slab index i in 0..8
    const int wl6  = (wl < 6) ? wl : 6;
    const int widx = wave * 7 + wl6;      // 0..13
    const int s    = s0 + widx;
    const bool act = (wl < 7) && (s < NS);

    float S3[9][9];
    float S2r[9];
    float S1i = 0.0f;
#pragma unroll
    for (int a = 0; a < 9; ++a) {
        S2r[a] = 0.0f;
#pragma unroll
        for (int c = 0; c < 9; ++c) S3[a][c] = 0.0f;
    }
    float prev[8];
#pragma unroll
    for (int c = 0; c < 8; ++c) prev[c] = 0.0f;
    float pscal = 0.0f;
    const int ioff = (ci > 0) ? (ci - 1) : 0;
    const int sm59 = s - 59;
    const float DT = 1.0f / 59.0f;

#pragma unroll 1
    for (int j = 0; j < 60; ++j) {
        int g = sm59 + j; g = (g > 0) ? g : 0;          // left-clamped window index
        const float* row = &X[(g - lo) * 8];
        const float4 c0 = *(const float4*)(row);
        const float4 c1 = *(const float4*)(row + 4);
        const float rs  = row[ioff];                    // scalar for this lane's slab
        const float dtj = (j == 0) ? 0.0f : DT;         // time-channel increment
        float v[9];
        v[0] = dtj;
        v[1] = c0.x - prev[0]; v[2] = c0.y - prev[1];
        v[3] = c0.z - prev[2]; v[4] = c0.w - prev[3];
        v[5] = c1.x - prev[4]; v[6] = c1.y - prev[5];
        v[7] = c1.z - prev[6]; v[8] = c1.w - prev[7];
        const float vi = (ci == 0) ? dtj : (rs - pscal);
        // S3 update first (old S1, S2):  S3[j][k] += (S2r[j] + (S1i/2 + vi/6)*v[j]) * v[k]
        const float hh = 0.5f * S1i + vi * (1.0f / 6.0f);
#pragma unroll
        for (int a = 0; a < 9; ++a) {
            const float ra = S2r[a] + hh * v[a];
#pragma unroll
            for (int c = 0; c < 9; ++c) S3[a][c] += ra * v[c];
        }
        // S2 update (old S1):  S2r[j] += (S1i + vi/2) * v[j]
        const float aa = S1i + 0.5f * vi;
#pragma unroll
        for (int a = 0; a < 9; ++a) S2r[a] += aa * v[a];
        S1i += vi;
        prev[0] = c0.x; prev[1] = c0.y; prev[2] = c0.z; prev[3] = c0.w;
        prev[4] = c1.x; prev[5] = c1.y; prev[6] = c1.z; prev[7] = c1.w;
        pscal = rs;
    }

    // cross-slab exchange (once): full S1 and S2 of each window into LDS
    if (wl < 7) {
        S1buf[widx * 9 + ci] = S1i;
#pragma unroll
        for (int a = 0; a < 9; ++a) S2buf[widx * 81 + ci * 9 + a] = S2r[a];
    }
    __syncthreads();

    float s1v[9];
#pragma unroll
    for (int a = 0; a < 9; ++a) s1v[a] = S1buf[widx * 9 + a];
    const float* S2w = &S2buf[widx * 81];

    __hip_bfloat16* frow = feats + (size_t)(b * NS + (act ? s : 0)) * KPAD;
    if (act) {
        // L1 = S1
        frow[ci] = __float2bfloat16(S1i);
        // L2[i,j] = S2[i,j] - 0.5 S1_i S1_j   (i<j), col = 9 + rank
#pragma unroll
        for (int j2 = 0; j2 < 9; ++j2) {
            if (ci < j2) {
                const float val = S2r[j2] - 0.5f * S1i * s1v[j2];
                const int col = 9 + ci * 8 - (ci * (ci - 1)) / 2 + (j2 - ci - 1);
                frow[col] = __float2bfloat16(val);
            }
        }
        if (ci == 0) {  // zero the K padding
            frow[285] = __float2bfloat16(0.0f);
            frow[286] = __float2bfloat16(0.0f);
            frow[287] = __float2bfloat16(0.0f);
        }
    }
    // L3[i,j,k] = S3 - 0.5(S1_i S2[j,k] + S2[i,j] S1_k) + S1_i S1_j S1_k / 3
    // nested constant-trip loops: every S3[j3][k3] index is compile-time
    const int tb = ci * 81;
#pragma unroll
    for (int j3 = 0; j3 < 9; ++j3) {
#pragma unroll
        for (int k3 = 0; k3 < 9; ++k3) {
            const int col = TBL3.col[tb + j3 * 9 + k3];
            if (act && col >= 0) {
                const float s2jk = S2w[j3 * 9 + k3];
                const float val = S3[j3][k3]
                    - 0.5f * (S1i * s2jk + S2r[j3] * s1v[k3])
                    + S1i * s1v[j3] * s1v[k3] * (1.0f / 3.0f);
                frow[col] = __float2bfloat16(val);
            }
        }
    }
}

// ============================================================================
// Weight transpose/cast kernels (tiny): w1[285][512]f32 -> w1T[512][288]bf16,
// w2[512][256]f32 -> w2T[256][512]bf16.  [n][k] layout => B-frag ds_read_b128.
// ============================================================================
__global__ void convert_w1(const float* __restrict__ w1, __hip_bfloat16* __restrict__ w1T) {
    const int n = blockIdx.x;          // 0..511
    const int k = threadIdx.x;         // 0..287
    const float v = (k < 285) ? w1[(size_t)k * H2 + n] : 0.0f;
    w1T[(size_t)n * KPAD + k] = __float2bfloat16(v);
}
__global__ void convert_w2(const float* __restrict__ w2, __hip_bfloat16* __restrict__ w2T) {
    const int n = blockIdx.x;          // 0..255
    const int k = threadIdx.x;         // 0..511
    w2T[(size_t)n * H2 + k] = __float2bfloat16(w2[(size_t)k * HID + n]);
}

// ============================================================================
// GEMM1: h = LN(GELU(feats @ w1 + b1)) -> bf16.  Block = 64 rows x 512 cols
// (full N so LN is fusable).  8 waves, wave tile 64x64, 16x16x32 bf16 MFMA.
// amdgpu_waves_per_eu(1,4): budget 128 VGPR so the 64-float acc never spills.
// ============================================================================
__global__ __launch_bounds__(512) __attribute__((amdgpu_waves_per_eu(1, 4)))
void gemm1_kernel(
        const __hip_bfloat16* __restrict__ feats,
        const __hip_bfloat16* __restrict__ w1T,
        const float* __restrict__ b1,
        const float* __restrict__ lng,
        const float* __restrict__ lnb,
        __hip_bfloat16* __restrict__ hbuf) {
    __shared__ __align__(16) __hip_bfloat16 ldsA[64 * 32];
    __shared__ __align__(16) __hip_bfloat16 ldsB[512 * 32];
    __shared__ float lnpart[8][64][2];
    __shared__ float lnstat[64][2];

    const int tid  = threadIdx.x;
    const int wave = tid >> 6;
    const int lane = tid & 63;
    const int quad = lane >> 4;
    const int l16  = lane & 15;
    const int m0   = blockIdx.x * 64;

    f32x4 acc[4][4];
#pragma unroll
    for (int mf = 0; mf < 4; ++mf)
#pragma unroll
        for (int nf = 0; nf < 4; ++nf) acc[mf][nf] = (f32x4){0.f, 0.f, 0.f, 0.f};

    for (int kt = 0; kt < 9; ++kt) {
        const int K0 = kt * 32;
        if (tid < 256) {               // A tile 64x32: waves 0-3, lane order == LDS order
            const int m = tid >> 2, kc = tid & 3;
            gl2lds16(feats + (size_t)(m0 + m) * KPAD + K0 + kc * 8,
                     (char*)ldsA + (tid & ~63) * 16);
        }
#pragma unroll
        for (int q = 0; q < 4; ++q) {  // B tile 512x32 ([n][k])
            const int chunk = q * 512 + tid;
            const int n = chunk >> 2, kc = chunk & 3;
            gl2lds16(w1T + (size_t)n * KPAD + K0 + kc * 8,
                     (char*)ldsB + (chunk & ~63) * 16);
        }
        __syncthreads();
        short8 bfrag[4];
#pragma unroll
        for (int nf = 0; nf < 4; ++nf) {
            const int n = wave * 64 + nf * 16 + l16;
            bfrag[nf] = *(const short8*)(ldsB + n * 32 + quad * 8);
        }
#pragma unroll
        for (int mf = 0; mf < 4; ++mf) {
            const short8 afrag = *(const short8*)(ldsA + (mf * 16 + l16) * 32 + quad * 8);
#pragma unroll
            for (int nf = 0; nf < 4; ++nf)
                acc[mf][nf] = __builtin_amdgcn_mfma_f32_16x16x32_bf16(afrag, bfrag[nf], acc[mf][nf], 0, 0, 0);
        }
        __syncthreads();
    }

    // ---- epilogue: bias + exact GELU IN PLACE (C frag: row = quad*4+reg, col = l16) ----
    float bias[4];
#pragma unroll
    for (int nf = 0; nf < 4; ++nf) bias[nf] = b1[wave * 64 + nf * 16 + l16];
#pragma unroll
    for (int mf = 0; mf < 4; ++mf)
#pragma unroll
        for (int nf = 0; nf < 4; ++nf)
#pragma unroll
            for (int r = 0; r < 4; ++r) {
                const float xv = acc[mf][nf][r] + bias[nf];
                acc[mf][nf][r] = 0.5f * xv * (1.0f + erff(xv * 0.70710678118654752f));
            }
    // LayerNorm: per-row sum/sumsq; reduce over 16 lanes (cols) then 8 waves
    float psum[4][4], psq[4][4];
#pragma unroll
    for (int mf = 0; mf < 4; ++mf)
#pragma unroll
        for (int r = 0; r < 4; ++r) {
            float su = 0.f, sq = 0.f;
#pragma unroll
            for (int nf = 0; nf < 4; ++nf) { const float t = acc[mf][nf][r]; su += t; sq += t * t; }
            psum[mf][r] = su; psq[mf][r] = sq;
        }
#pragma unroll
    for (int d = 1; d < 16; d <<= 1) {
#pragma unroll
        for (int mf = 0; mf < 4; ++mf)
#pragma unroll
            for (int r = 0; r < 4; ++r) {
                psum[mf][r] += __shfl_xor(psum[mf][r], d);
                psq[mf][r]  += __shfl_xor(psq[mf][r], d);
            }
    }
    if (l16 == 0) {
#pragma unroll
        for (int mf = 0; mf < 4; ++mf)
#pragma unroll
            for (int r = 0; r < 4; ++r) {
                const int rrow = mf * 16 + quad * 4 + r;
                lnpart[wave][rrow][0] = psum[mf][r];
                lnpart[wave][rrow][1] = psq[mf][r];
            }
    }
    __syncthreads();
    if (tid < 64) {
        float su = 0.f, sq = 0.f;
#pragma unroll
        for (int w = 0; w < 8; ++w) { su += lnpart[w][tid][0]; sq += lnpart[w][tid][1]; }
        const float mu  = su * (1.0f / 512.0f);
        const float var = sq * (1.0f / 512.0f) - mu * mu;   // population var (ddof=0)
        lnstat[tid][0] = mu;
        lnstat[tid][1] = rsqrtf(var + 1e-5f);
    }
    __syncthreads();
    float gv[4], bv[4];
#pragma unroll
    for (int nf = 0; nf < 4; ++nf) {
        const int col = wave * 64 + nf * 16 + l16;
        gv[nf] = lng[col]; bv[nf] = lnb[col];
    }
#pragma unroll
    for (int mf = 0; mf < 4; ++mf)
#pragma unroll
        for (int r = 0; r < 4; ++r) {
            const int rrow = mf * 16 + quad * 4 + r;
            const float mu = lnstat[rrow][0];
            const float rstd = lnstat[rrow][1];
#pragma unroll
            for (int nf = 0; nf < 4; ++nf) {
                const float hn = (acc[mf][nf][r] - mu) * rstd * gv[nf] + bv[nf];
                hbuf[(size_t)(m0 + rrow) * H2 + wave * 64 + nf * 16 + l16] = __float2bfloat16(hn);
            }
        }
}

// ============================================================================
// GEMM2: out = h @ w2 + b2 (fp32 out). Block = 64 rows x 256 cols, 8 waves,
// wave tile 64x32, K=512 in 16 steps of 32.
// ============================================================================
__global__ __launch_bounds__(512) __attribute__((amdgpu_waves_per_eu(1, 4)))
void gemm2_kernel(
        const __hip_bfloat16* __restrict__ hbuf,
        const __hip_bfloat16* __restrict__ w2T,
        const float* __restrict__ b2,
        float* __restrict__ out) {
    __shared__ __align__(16) __hip_bfloat16 ldsA[64 * 32];
    __shared__ __align__(16) __hip_bfloat16 ldsB[256 * 32];
    const int tid  = threadIdx.x;
    const int wave = tid >> 6;
    const int lane = tid & 63;
    const int quad = lane >> 4;
    const int l16  = lane & 15;
    const int m0   = blockIdx.x * 64;

    f32x4 acc[4][2];
#pragma unroll
    for (int mf = 0; mf < 4; ++mf)
#pragma unroll
        for (int nf = 0; nf < 2; ++nf) acc[mf][nf] = (f32x4){0.f, 0.f, 0.f, 0.f};

    for (int kt = 0; kt < 16; ++kt) {
        const int K0 = kt * 32;
        if (tid < 256) {
            const int m = tid >> 2, kc = tid & 3;
            gl2lds16(hbuf + (size_t)(m0 + m) * H2 + K0 + kc * 8,
                     (char*)ldsA + (tid & ~63) * 16);
        }
#pragma unroll
        for (int q = 0; q < 2; ++q) {
            const int chunk = q * 512 + tid;
            const int n = chunk >> 2, kc = chunk & 3;
            gl2lds16(w2T + (size_t)n * H2 + K0 + kc * 8,
                     (char*)ldsB + (chunk & ~63) * 16);
        }
        __syncthreads();
        short8 bfrag[2];
#pragma unroll
        for (int nf = 0; nf < 2; ++nf) {
            const int n = wave * 32 + nf * 16 + l16;
            bfrag[nf] = *(const short8*)(ldsB + n * 32 + quad * 8);
        }
#pragma unroll
        for (int mf = 0; mf < 4; ++mf) {
            const short8 afrag = *(const short8*)(ldsA + (mf * 16 + l16) * 32 + quad * 8);
#pragma unroll
            for (int nf = 0; nf < 2; ++nf)
                acc[mf][nf] = __builtin_amdgcn_mfma_f32_16x16x32_bf16(afrag, bfrag[nf], acc[mf][nf], 0, 0, 0);
        }
        __syncthreads();
    }
    float bb[2];
#pragma unroll
    for (int nf = 0; nf < 2; ++nf) bb[nf] = b2[wave * 32 + nf * 16 + l16];
#pragma unroll
    for (int mf = 0; mf < 4; ++mf)
#pragma unroll
        for (int r = 0; r < 4; ++r) {
            const int rrow = mf * 16 + quad * 4 + r;
#pragma unroll
            for (int nf = 0; nf < 2; ++nf)
                out[(size_t)(m0 + rrow) * HID + wave * 32 + nf * 16 + l16] = acc[mf][nf][r] + bb[nf];
        }
}

// ============================================================================
extern "C" void kernel_launch(void* const* d_in, const int* in_sizes, int n_in,
                              void* d_out, int out_size, void* d_ws, size_t ws_size,
                              hipStream_t stream) {
    const float* x   = (const float*)d_in[0];
    const float* w1  = (const float*)d_in[1];
    const float* b1  = (const float*)d_in[2];
    const float* lng = (const float*)d_in[3];
    const float* lnb = (const float*)d_in[4];
    const float* w2  = (const float*)d_in[5];
    const float* b2  = (const float*)d_in[6];
    float* out = (float*)d_out;

    char* ws = (char*)d_ws;
    __hip_bfloat16* feats = (__hip_bfloat16*)(ws);                       // 16384*288*2 = 9437184
    __hip_bfloat16* hbuf  = (__hip_bfloat16*)(ws + 9437184);             // 16384*512*2 = 16777216
    __hip_bfloat16* w1T   = (__hip_bfloat16*)(ws + 9437184 + 16777216);  // 512*288*2  = 294912
    __hip_bfloat16* w2T   = (__hip_bfloat16*)(ws + 9437184 + 16777216 + 294912); // 256*512*2

    convert_w1<<<dim3(512), dim3(288), 0, stream>>>(w1, w1T);
    convert_w2<<<dim3(256), dim3(512), 0, stream>>>(w2, w2T);
    sig_kernel<<<dim3(8 * SBLK), dim3(128), 0, stream>>>(x, feats);
    gemm1_kernel<<<dim3(16384 / 64), dim3(512), 0, stream>>>(feats, w1T, b1, lng, lnb, hbuf);
    gemm2_kernel<<<dim3(16384 / 64), dim3(512), 0, stream>>>(hbuf, w2T, b2, out);
}

// Round 4
// 175.812 us; speedup vs baseline: 1.0318x; 1.0318x over previous
//
#include <hip/hip_runtime.h>
#include <hip/hip_bf16.h>
#include <cstdint>
#include <cstddef>

typedef short short8 __attribute__((ext_vector_type(8)));
typedef float f32x4 __attribute__((ext_vector_type(4)));

#define NS    2048
#define KPAD  288     // 285 sig channels padded to 288
#define H2    512
#define HID   256
#define WPB   14      // windows per sig workgroup (2 waves x 7)
#define SBLK  147     // ceil(2048/14)

// async global->LDS 16B: dst must be the WAVE-UNIFORM base; lane i lands at dst + i*16
__device__ __forceinline__ void gl2lds16(const void* g, void* l) {
    __builtin_amdgcn_global_load_lds(
        (const __attribute__((address_space(1))) void*)g,
        (__attribute__((address_space(3))) void*)l, 16, 0, 0);
}

__device__ __forceinline__ float geluf(float x) {
    return 0.5f * x * (1.0f + erff(x * 0.70710678118654752f));
}

__device__ __forceinline__ f32x4 shfl4(f32x4 v, int d) {
    f32x4 r;
    r[0] = __shfl_xor(v[0], d); r[1] = __shfl_xor(v[1], d);
    r[2] = __shfl_xor(v[2], d); r[3] = __shfl_xor(v[3], d);
    return r;
}

// ---- compile-time necklace-representative table: (i,j,k) -> feat col (45+rank) or -1
struct Tbl3 { short col[729]; };
static constexpr Tbl3 make_tbl3() {
    Tbl3 t{};
    for (int x = 0; x < 729; ++x) t.col[x] = -1;
    int r = 0;
    for (int i = 0; i < 9; ++i)
        for (int j = 0; j < 9; ++j)
            for (int k = 0; k < 9; ++k) {
                bool lt1 = (i < j) || (i == j && (j < k || (j == k && k < i)));
                bool lt2 = (i < k) || (i == k && (j < i || (j == i && k < j)));
                if (lt1 && lt2) { t.col[(i*9+j)*9+k] = (short)(45 + r); ++r; }
            }
    return t;
}
static constexpr Tbl3 TBL3 = make_tbl3();

// ============================================================================
// SSA-only signature kernel.  ROUND-3 LESSON: local arrays (S3[9][9] etc.)
// were never SROA-promoted (variable GEP indices at SROA time) -> permanent
// scratch allocas -> 9.2 GB scratch writes regardless of waves_per_eu.
// All state is now NAMED SCALARS -> allocas cannot exist.
// ============================================================================
#define SIG_DECLROW(a) \
    float S3_##a##_0=0.f,S3_##a##_1=0.f,S3_##a##_2=0.f,S3_##a##_3=0.f,S3_##a##_4=0.f, \
          S3_##a##_5=0.f,S3_##a##_6=0.f,S3_##a##_7=0.f,S3_##a##_8=0.f;
#define SIG_CHENROW(a) { const float ra = S2r##a + hh * v##a; \
    S3_##a##_0 += ra*v0; S3_##a##_1 += ra*v1; S3_##a##_2 += ra*v2; \
    S3_##a##_3 += ra*v3; S3_##a##_4 += ra*v4; S3_##a##_5 += ra*v5; \
    S3_##a##_6 += ra*v6; S3_##a##_7 += ra*v7; S3_##a##_8 += ra*v8; }
#define SIG_EMIT2(j2) if (ci < j2) { \
    const float val2 = S2r##j2 - 0.5f * S1i * s1v##j2; \
    const int col2 = 9 + ci*8 - (ci*(ci-1))/2 + (j2 - ci - 1); \
    frow[col2] = __float2bfloat16(val2); }
#define SIG_EMIT3(j3,k3) { const int col3 = TBL3.col[tb + j3*9 + k3]; \
    if (act && col3 >= 0) { \
        const float val3 = S3_##j3##_##k3 \
            - 0.5f * (S1i * S2w[j3*9+k3] + S2r##j3 * s1v##k3) \
            + S1i * s1v##j3 * s1v##k3 * (1.0f/3.0f); \
        frow[col3] = __float2bfloat16(val3); } }
#define SIG_EMIT3R(j3) SIG_EMIT3(j3,0) SIG_EMIT3(j3,1) SIG_EMIT3(j3,2) SIG_EMIT3(j3,3) \
    SIG_EMIT3(j3,4) SIG_EMIT3(j3,5) SIG_EMIT3(j3,6) SIG_EMIT3(j3,7) SIG_EMIT3(j3,8)

__global__ __launch_bounds__(128) __attribute__((amdgpu_waves_per_eu(1, 3)))
void sig_kernel(const float* __restrict__ x, __hip_bfloat16* __restrict__ feats) {
    __shared__ __align__(16) float X[73 * 8];
    __shared__ float S2buf[WPB * 81];
    __shared__ float S1buf[WPB * 9];

    const int blk = blockIdx.x;
    const int b   = blk / SBLK;
    const int s0  = (blk % SBLK) * WPB;
    const int lo  = (s0 - 59 > 0) ? (s0 - 59) : 0;
    const int hi  = (s0 + WPB - 1 < NS - 1) ? (s0 + WPB - 1) : (NS - 1);
    const int nrow = hi - lo + 1;     // <= 73
    const int tid = threadIdx.x;

    {   // stage x[b, lo..hi, 0..7] -> LDS (row-major [pos][ch])
        const float4* src = (const float4*)(x + ((size_t)b * NS + lo) * 8);
        float4* dst = (float4*)X;
        const int n4 = nrow * 2;
        for (int t = tid; t < n4; t += 128) dst[t] = src[t];
    }
    __syncthreads();

    const int lane = tid & 63;
    const int wave = tid >> 6;
    const int wl   = lane / 9;            // 0..7 (7 == idle duplicate lane)
    const int ci   = lane - wl * 9;       // slab index i in 0..8
    const int wl6  = (wl < 6) ? wl : 6;
    const int widx = wave * 7 + wl6;      // 0..13
    const int s    = s0 + widx;
    const bool act = (wl < 7) && (s < NS);

    SIG_DECLROW(0) SIG_DECLROW(1) SIG_DECLROW(2) SIG_DECLROW(3) SIG_DECLROW(4)
    SIG_DECLROW(5) SIG_DECLROW(6) SIG_DECLROW(7) SIG_DECLROW(8)
    float S2r0=0.f,S2r1=0.f,S2r2=0.f,S2r3=0.f,S2r4=0.f,S2r5=0.f,S2r6=0.f,S2r7=0.f,S2r8=0.f;
    float S1i = 0.f;
    float prev0=0.f,prev1=0.f,prev2=0.f,prev3=0.f,prev4=0.f,prev5=0.f,prev6=0.f,prev7=0.f;
    float pscal = 0.f;
    const int ioff = (ci > 0) ? (ci - 1) : 0;
    const int sm59 = s - 59;
    const float DT = 1.0f / 59.0f;

#pragma unroll 1
    for (int j = 0; j < 60; ++j) {
        int g = sm59 + j; g = (g > 0) ? g : 0;          // left-clamped window index
        const float* row = &X[(g - lo) * 8];
        const float4 c0 = *(const float4*)(row);
        const float4 c1 = *(const float4*)(row + 4);
        const float rs  = row[ioff];                    // scalar for this lane's slab
        const float dtj = (j == 0) ? 0.0f : DT;         // time-channel increment
        const float v0 = dtj;
        const float v1 = c0.x - prev0, v2 = c0.y - prev1, v3 = c0.z - prev2, v4 = c0.w - prev3;
        const float v5 = c1.x - prev4, v6 = c1.y - prev5, v7 = c1.z - prev6, v8 = c1.w - prev7;
        const float vi = (ci == 0) ? dtj : (rs - pscal);
        // S3 update first (old S1, S2):  S3[j][k] += (S2r[j] + (S1i/2 + vi/6)*v[j]) * v[k]
        const float hh = 0.5f * S1i + vi * (1.0f / 6.0f);
        SIG_CHENROW(0) SIG_CHENROW(1) SIG_CHENROW(2) SIG_CHENROW(3) SIG_CHENROW(4)
        SIG_CHENROW(5) SIG_CHENROW(6) SIG_CHENROW(7) SIG_CHENROW(8)
        // S2 update (old S1):  S2r[j] += (S1i + vi/2) * v[j]
        const float aa = S1i + 0.5f * vi;
        S2r0 += aa*v0; S2r1 += aa*v1; S2r2 += aa*v2; S2r3 += aa*v3; S2r4 += aa*v4;
        S2r5 += aa*v5; S2r6 += aa*v6; S2r7 += aa*v7; S2r8 += aa*v8;
        S1i += vi;
        prev0 = c0.x; prev1 = c0.y; prev2 = c0.z; prev3 = c0.w;
        prev4 = c1.x; prev5 = c1.y; prev6 = c1.z; prev7 = c1.w;
        pscal = rs;
    }

    // cross-slab exchange (once): full S1 and S2 of each window into LDS
    if (wl < 7) {
        S1buf[widx * 9 + ci] = S1i;
        float* sb = &S2buf[widx * 81 + ci * 9];
        sb[0]=S2r0; sb[1]=S2r1; sb[2]=S2r2; sb[3]=S2r3; sb[4]=S2r4;
        sb[5]=S2r5; sb[6]=S2r6; sb[7]=S2r7; sb[8]=S2r8;
    }
    __syncthreads();

    const float* s1p = &S1buf[widx * 9];
    const float s1v0=s1p[0], s1v1=s1p[1], s1v2=s1p[2], s1v3=s1p[3], s1v4=s1p[4];
    const float s1v5=s1p[5], s1v6=s1p[6], s1v7=s1p[7], s1v8=s1p[8];
    const float* S2w = &S2buf[widx * 81];

    __hip_bfloat16* frow = feats + (size_t)(b * NS + (act ? s : 0)) * KPAD;
    if (act) {
        // L1 = S1
        frow[ci] = __float2bfloat16(S1i);
        // L2[i,j] = S2[i,j] - 0.5 S1_i S1_j   (i<j), col = 9 + rank
        SIG_EMIT2(1) SIG_EMIT2(2) SIG_EMIT2(3) SIG_EMIT2(4)
        SIG_EMIT2(5) SIG_EMIT2(6) SIG_EMIT2(7) SIG_EMIT2(8)
        if (ci == 0) {  // zero the K padding
            frow[285] = __float2bfloat16(0.0f);
            frow[286] = __float2bfloat16(0.0f);
            frow[287] = __float2bfloat16(0.0f);
        }
    }
    // L3[i,j,k] = S3 - 0.5(S1_i S2[j,k] + S2[i,j] S1_k) + S1_i S1_j S1_k / 3
    const int tb = ci * 81;
    SIG_EMIT3R(0) SIG_EMIT3R(1) SIG_EMIT3R(2) SIG_EMIT3R(3) SIG_EMIT3R(4)
    SIG_EMIT3R(5) SIG_EMIT3R(6) SIG_EMIT3R(7) SIG_EMIT3R(8)
}

// ============================================================================
// Weight transpose/cast kernels (tiny)
// ============================================================================
__global__ void convert_w1(const float* __restrict__ w1, __hip_bfloat16* __restrict__ w1T) {
    const int n = blockIdx.x;          // 0..511
    const int k = threadIdx.x;         // 0..287
    const float v = (k < 285) ? w1[(size_t)k * H2 + n] : 0.0f;
    w1T[(size_t)n * KPAD + k] = __float2bfloat16(v);
}
__global__ void convert_w2(const float* __restrict__ w2, __hip_bfloat16* __restrict__ w2T) {
    const int n = blockIdx.x;          // 0..255
    const int k = threadIdx.x;         // 0..511
    w2T[(size_t)n * H2 + k] = __float2bfloat16(w2[(size_t)k * HID + n]);
}

// ============================================================================
// GEMM1: h = LN(GELU(feats @ w1 + b1)) -> bf16.  Block = 64 rows x 512 cols,
// 8 waves, wave tile 64x64, 16x16x32 bf16 MFMA.  Accumulators are NAMED
// f32x4 SSA values (no arrays -> no allocas -> no scratch).
// ============================================================================
#define G1_DECLACC(m) f32x4 acc##m##0 = {0.f,0.f,0.f,0.f}, acc##m##1 = {0.f,0.f,0.f,0.f}, \
                            acc##m##2 = {0.f,0.f,0.f,0.f}, acc##m##3 = {0.f,0.f,0.f,0.f};
#define G1_MFMA(m) { const short8 afr = *(const short8*)(ldsA + ((m)*16 + l16)*32 + quad*8); \
    acc##m##0 = __builtin_amdgcn_mfma_f32_16x16x32_bf16(afr, bfrag0, acc##m##0, 0,0,0); \
    acc##m##1 = __builtin_amdgcn_mfma_f32_16x16x32_bf16(afr, bfrag1, acc##m##1, 0,0,0); \
    acc##m##2 = __builtin_amdgcn_mfma_f32_16x16x32_bf16(afr, bfrag2, acc##m##2, 0,0,0); \
    acc##m##3 = __builtin_amdgcn_mfma_f32_16x16x32_bf16(afr, bfrag3, acc##m##3, 0,0,0); }
#define G1_GELU1(m,n) { \
    acc##m##n[0]=geluf(acc##m##n[0]+bias##n); acc##m##n[1]=geluf(acc##m##n[1]+bias##n); \
    acc##m##n[2]=geluf(acc##m##n[2]+bias##n); acc##m##n[3]=geluf(acc##m##n[3]+bias##n); }
#define G1_GELUR(m) G1_GELU1(m,0) G1_GELU1(m,1) G1_GELU1(m,2) G1_GELU1(m,3)
#define G1_LNS(m) f32x4 psum##m = acc##m##0 + acc##m##1 + acc##m##2 + acc##m##3; \
    f32x4 psq##m = acc##m##0*acc##m##0 + acc##m##1*acc##m##1 + acc##m##2*acc##m##2 + acc##m##3*acc##m##3;
#define G1_STP(m) { const int rrp = (m)*16 + quad*4; \
    lnpart[wave][rrp+0][0]=psum##m[0]; lnpart[wave][rrp+0][1]=psq##m[0]; \
    lnpart[wave][rrp+1][0]=psum##m[1]; lnpart[wave][rrp+1][1]=psq##m[1]; \
    lnpart[wave][rrp+2][0]=psum##m[2]; lnpart[wave][rrp+2][1]=psq##m[2]; \
    lnpart[wave][rrp+3][0]=psum##m[3]; lnpart[wave][rrp+3][1]=psq##m[3]; }
#define G1_LDST(m) f32x4 mu##m; f32x4 rstd##m; { const int rrl = (m)*16 + quad*4; \
    mu##m[0]=lnstat[rrl+0][0]; mu##m[1]=lnstat[rrl+1][0]; mu##m[2]=lnstat[rrl+2][0]; mu##m[3]=lnstat[rrl+3][0]; \
    rstd##m[0]=lnstat[rrl+0][1]; rstd##m[1]=lnstat[rrl+1][1]; rstd##m[2]=lnstat[rrl+2][1]; rstd##m[3]=lnstat[rrl+3][1]; }
#define G1_OUT(m,n) { const int colo = wave*64 + (n)*16 + l16; \
    f32x4 hv = (acc##m##n - mu##m) * rstd##m * gv##n + bv##n; \
    const int rro = (m)*16 + quad*4; \
    hbuf[(size_t)(m0+rro+0)*H2 + colo] = __float2bfloat16(hv[0]); \
    hbuf[(size_t)(m0+rro+1)*H2 + colo] = __float2bfloat16(hv[1]); \
    hbuf[(size_t)(m0+rro+2)*H2 + colo] = __float2bfloat16(hv[2]); \
    hbuf[(size_t)(m0+rro+3)*H2 + colo] = __float2bfloat16(hv[3]); }
#define G1_OUTR(m) G1_OUT(m,0) G1_OUT(m,1) G1_OUT(m,2) G1_OUT(m,3)

__global__ __launch_bounds__(512) __attribute__((amdgpu_waves_per_eu(1, 3)))
void gemm1_kernel(
        const __hip_bfloat16* __restrict__ feats,
        const __hip_bfloat16* __restrict__ w1T,
        const float* __restrict__ b1,
        const float* __restrict__ lng,
        const float* __restrict__ lnb,
        __hip_bfloat16* __restrict__ hbuf) {
    __shared__ __align__(16) __hip_bfloat16 ldsA[64 * 32];
    __shared__ __align__(16) __hip_bfloat16 ldsB[512 * 32];
    __shared__ float lnpart[8][64][2];
    __shared__ float lnstat[64][2];

    const int tid  = threadIdx.x;
    const int wave = tid >> 6;
    const int lane = tid & 63;
    const int quad = lane >> 4;
    const int l16  = lane & 15;
    const int m0   = blockIdx.x * 64;

    G1_DECLACC(0) G1_DECLACC(1) G1_DECLACC(2) G1_DECLACC(3)

#pragma unroll 1
    for (int kt = 0; kt < 9; ++kt) {
        const int K0 = kt * 32;
        if (tid < 256) {               // A tile 64x32: waves 0-3, lane order == LDS order
            const int m = tid >> 2, kc = tid & 3;
            gl2lds16(feats + (size_t)(m0 + m) * KPAD + K0 + kc * 8,
                     (char*)ldsA + (tid & ~63) * 16);
        }
#pragma unroll
        for (int q = 0; q < 4; ++q) {  // B tile 512x32 ([n][k])
            const int chunk = q * 512 + tid;
            const int n = chunk >> 2, kc = chunk & 3;
            gl2lds16(w1T + (size_t)n * KPAD + K0 + kc * 8,
                     (char*)ldsB + (chunk & ~63) * 16);
        }
        __syncthreads();
        const __hip_bfloat16* bbase = ldsB + (wave * 64 + l16) * 32 + quad * 8;
        const short8 bfrag0 = *(const short8*)(bbase);
        const short8 bfrag1 = *(const short8*)(bbase + 16 * 32);
        const short8 bfrag2 = *(const short8*)(bbase + 32 * 32);
        const short8 bfrag3 = *(const short8*)(bbase + 48 * 32);
        G1_MFMA(0) G1_MFMA(1) G1_MFMA(2) G1_MFMA(3)
        __syncthreads();
    }

    // ---- epilogue: bias + exact GELU in place (C frag: row = quad*4+reg, col = l16) ----
    const float bias0 = b1[wave*64 +  0 + l16];
    const float bias1 = b1[wave*64 + 16 + l16];
    const float bias2 = b1[wave*64 + 32 + l16];
    const float bias3 = b1[wave*64 + 48 + l16];
    G1_GELUR(0) G1_GELUR(1) G1_GELUR(2) G1_GELUR(3)

    // LayerNorm: per-row sum/sumsq; reduce over 16 lanes (cols) then 8 waves
    G1_LNS(0) G1_LNS(1) G1_LNS(2) G1_LNS(3)
#pragma unroll
    for (int d = 1; d < 16; d <<= 1) {
        psum0 += shfl4(psum0, d); psq0 += shfl4(psq0, d);
        psum1 += shfl4(psum1, d); psq1 += shfl4(psq1, d);
        psum2 += shfl4(psum2, d); psq2 += shfl4(psq2, d);
        psum3 += shfl4(psum3, d); psq3 += shfl4(psq3, d);
    }
    if (l16 == 0) { G1_STP(0) G1_STP(1) G1_STP(2) G1_STP(3) }
    __syncthreads();
    if (tid < 64) {
        float su = 0.f, sq = 0.f;
#pragma unroll
        for (int w = 0; w < 8; ++w) { su += lnpart[w][tid][0]; sq += lnpart[w][tid][1]; }
        const float mu  = su * (1.0f / 512.0f);
        const float var = sq * (1.0f / 512.0f) - mu * mu;   // population var (ddof=0)
        lnstat[tid][0] = mu;
        lnstat[tid][1] = rsqrtf(var + 1e-5f);
    }
    __syncthreads();
    const float gv0 = lng[wave*64 +  0 + l16], bv0 = lnb[wave*64 +  0 + l16];
    const float gv1 = lng[wave*64 + 16 + l16], bv1 = lnb[wave*64 + 16 + l16];
    const float gv2 = lng[wave*64 + 32 + l16], bv2 = lnb[wave*64 + 32 + l16];
    const float gv3 = lng[wave*64 + 48 + l16], bv3 = lnb[wave*64 + 48 + l16];
    G1_LDST(0) G1_LDST(1) G1_LDST(2) G1_LDST(3)
    G1_OUTR(0) G1_OUTR(1) G1_OUTR(2) G1_OUTR(3)
}

// ============================================================================
// GEMM2: out = h @ w2 + b2 (fp32 out). Block = 64 rows x 256 cols, 8 waves,
// wave tile 64x32, K=512 in 16 steps of 32.  Named SSA accumulators.
// ============================================================================
#define G2_DECL(m) f32x4 bcc##m##0 = {0.f,0.f,0.f,0.f}, bcc##m##1 = {0.f,0.f,0.f,0.f};
#define G2_MFMA(m) { const short8 afr = *(const short8*)(ldsA + ((m)*16 + l16)*32 + quad*8); \
    bcc##m##0 = __builtin_amdgcn_mfma_f32_16x16x32_bf16(afr, bfr0, bcc##m##0, 0,0,0); \
    bcc##m##1 = __builtin_amdgcn_mfma_f32_16x16x32_bf16(afr, bfr1, bcc##m##1, 0,0,0); }
#define G2_OUT(m) { const int rro = (m)*16 + quad*4; \
    out[(size_t)(m0+rro+0)*HID + c0i] = bcc##m##0[0] + bb0; \
    out[(size_t)(m0+rro+1)*HID + c0i] = bcc##m##0[1] + bb0; \
    out[(size_t)(m0+rro+2)*HID + c0i] = bcc##m##0[2] + bb0; \
    out[(size_t)(m0+rro+3)*HID + c0i] = bcc##m##0[3] + bb0; \
    out[(size_t)(m0+rro+0)*HID + c1i] = bcc##m##1[0] + bb1; \
    out[(size_t)(m0+rro+1)*HID + c1i] = bcc##m##1[1] + bb1; \
    out[(size_t)(m0+rro+2)*HID + c1i] = bcc##m##1[2] + bb1; \
    out[(size_t)(m0+rro+3)*HID + c1i] = bcc##m##1[3] + bb1; }

__global__ __launch_bounds__(512) __attribute__((amdgpu_waves_per_eu(1, 3)))
void gemm2_kernel(
        const __hip_bfloat16* __restrict__ hbuf,
        const __hip_bfloat16* __restrict__ w2T,
        const float* __restrict__ b2,
        float* __restrict__ out) {
    __shared__ __align__(16) __hip_bfloat16 ldsA[64 * 32];
    __shared__ __align__(16) __hip_bfloat16 ldsB[256 * 32];
    const int tid  = threadIdx.x;
    const int wave = tid >> 6;
    const int lane = tid & 63;
    const int quad = lane >> 4;
    const int l16  = lane & 15;
    const int m0   = blockIdx.x * 64;

    G2_DECL(0) G2_DECL(1) G2_DECL(2) G2_DECL(3)

#pragma unroll 1
    for (int kt = 0; kt < 16; ++kt) {
        const int K0 = kt * 32;
        if (tid < 256) {
            const int m = tid >> 2, kc = tid & 3;
            gl2lds16(hbuf + (size_t)(m0 + m) * H2 + K0 + kc * 8,
                     (char*)ldsA + (tid & ~63) * 16);
        }
#pragma unroll
        for (int q = 0; q < 2; ++q) {
            const int chunk = q * 512 + tid;
            const int n = chunk >> 2, kc = chunk & 3;
            gl2lds16(w2T + (size_t)n * H2 + K0 + kc * 8,
                     (char*)ldsB + (chunk & ~63) * 16);
        }
        __syncthreads();
        const __hip_bfloat16* bbase = ldsB + (wave * 32 + l16) * 32 + quad * 8;
        const short8 bfr0 = *(const short8*)(bbase);
        const short8 bfr1 = *(const short8*)(bbase + 16 * 32);
        G2_MFMA(0) G2_MFMA(1) G2_MFMA(2) G2_MFMA(3)
        __syncthreads();
    }
    const float bb0 = b2[wave*32 +  0 + l16];
    const float bb1 = b2[wave*32 + 16 + l16];
    const int c0i = wave*32 +  0 + l16;
    const int c1i = wave*32 + 16 + l16;
    G2_OUT(0) G2_OUT(1) G2_OUT(2) G2_OUT(3)
}

// ============================================================================
extern "C" void kernel_launch(void* const* d_in, const int* in_sizes, int n_in,
                              void* d_out, int out_size, void* d_ws, size_t ws_size,
                              hipStream_t stream) {
    const float* x   = (const float*)d_in[0];
    const float* w1  = (const float*)d_in[1];
    const float* b1  = (const float*)d_in[2];
    const float* lng = (const float*)d_in[3];
    const float* lnb = (const float*)d_in[4];
    const float* w2  = (const float*)d_in[5];
    const float* b2  = (const float*)d_in[6];
    float* out = (float*)d_out;

    char* ws = (char*)d_ws;
    __hip_bfloat16* feats = (__hip_bfloat16*)(ws);                       // 16384*288*2 = 9437184
    __hip_bfloat16* hbuf  = (__hip_bfloat16*)(ws + 9437184);             // 16384*512*2 = 16777216
    __hip_bfloat16* w1T   = (__hip_bfloat16*)(ws + 9437184 + 16777216);  // 512*288*2  = 294912
    __hip_bfloat16* w2T   = (__hip_bfloat16*)(ws + 9437184 + 16777216 + 294912); // 256*512*2

    convert_w1<<<dim3(512), dim3(288), 0, stream>>>(w1, w1T);
    convert_w2<<<dim3(256), dim3(512), 0, stream>>>(w2, w2T);
    sig_kernel<<<dim3(8 * SBLK), dim3(128), 0, stream>>>(x, feats);
    gemm1_kernel<<<dim3(16384 / 64), dim3(512), 0, stream>>>(feats, w1T, b1, lng, lnb, hbuf);
    gemm2_kernel<<<dim3(16384 / 64), dim3(512), 0, stream>>>(hbuf, w2T, b2, out);
}